// Round 10
// baseline (475.483 us; speedup 1.0000x reference)
//
#include <hip/hip_runtime.h>
#include <hip/hip_bf16.h>
#include <hip/hip_fp16.h>
#include <math.h>

// ---------------------------------------------------------------------------
// HomoGAT on MI355X.
//  - GEMMs: split-precision bf16 MFMA, pre-split guard-free operand tables,
//    2-phase pipelined k-loop: global_load_lds (16B) double-buffered staging,
//    ONE barrier per k-iter (issue next -> compute current -> syncthreads).
//  - feat1/feat2 gather tables fp16 (random-gather line-rate ceiling, R5-R8).
//  - Aggregation: CSR by dst, wave-per-node, precomputed edge weights,
//    8 fp16 rows in flight.
// ---------------------------------------------------------------------------

typedef __attribute__((ext_vector_type(8))) short bf16x8;
typedef __attribute__((ext_vector_type(4))) float f32x4;

typedef const __attribute__((address_space(1))) char gas_char;
typedef __attribute__((address_space(3))) char las_char;

__device__ __forceinline__ void gload16(const void* g, void* l) {
    __builtin_amdgcn_global_load_lds((gas_char*)g, (las_char*)l, 16, 0, 0);
}

__device__ __forceinline__ void split2(float v, short& h, short& l) {
    __hip_bfloat16 bh = __float2bfloat16(v);
    float r = v - __bfloat162float(bh);
    __hip_bfloat16 bl = __float2bfloat16(r);
    h = *reinterpret_cast<short*>(&bh);
    l = *reinterpret_cast<short*>(&bl);
}

__device__ __forceinline__ float fast_tanh(float x) {
    x = fminf(fmaxf(x, -15.f), 15.f);
    float e = __expf(2.f * x);
    return (e - 1.f) * __builtin_amdgcn_rcpf(e + 1.f);
}

__device__ __forceinline__ float leaky02(float x) { return x > 0.f ? x : 0.2f * x; }

__device__ __forceinline__ float sel_head(float4 q, int h) {
    float lo = (h & 1) ? q.y : q.x;
    float hi = (h & 1) ? q.w : q.z;
    return (h & 2) ? hi : lo;
}

// ---------------- weight split (all 3 weight matrices, transposed) ---------
__global__ __launch_bounds__(256) void wsplit3_kernel(
        const float* __restrict__ W0, short* __restrict__ B0h, short* __restrict__ B0l,
        const float* __restrict__ W1, short* __restrict__ B1h, short* __restrict__ B1l,
        const float* __restrict__ W2, short* __restrict__ B2h, short* __restrict__ B2l) {
    int idx = blockIdx.x * 256 + threadIdx.x;
    const float* W;
    short *Bh, *Bl;
    int K, rel;
    if (idx < 128 * 256) {
        W = W0; Bh = B0h; Bl = B0l; K = 128; rel = idx;
    } else if (idx < 128 * 256 + 256 * 256) {
        W = W1; Bh = B1h; Bl = B1l; K = 256; rel = idx - 128 * 256;
    } else if (idx < 128 * 256 + 2 * 256 * 256) {
        W = W2; Bh = B2h; Bl = B2l; K = 256; rel = idx - 128 * 256 - 256 * 256;
    } else {
        return;
    }
    int k = rel >> 8, n = rel & 255;
    short h, l;
    split2(W[rel], h, l);
    Bh[n * K + k] = h;
    Bl[n * K + k] = l;
}

// ---------------- x_feat split: fp32 -> bf16 h/l (row-major) ---------------
__global__ __launch_bounds__(256) void xsplit_kernel(const float* __restrict__ X,
                                                     short* __restrict__ Xh,
                                                     short* __restrict__ Xl, int total) {
    int idx = blockIdx.x * 256 + threadIdx.x;
    if (idx >= total) return;
    short h, l;
    split2(X[idx], h, l);
    Xh[idx] = h;
    Xl[idx] = l;
}

// ---------------- MFMA GEMM: C[M,256] = A[M,K] @ B[K,256] ------------------
// A pre-split (padded), B pre-split/transposed. 2-phase global_load_lds
// pipeline, one barrier per k-iter. K is compile-time (128 or 256).
template<int K, bool TANH, bool ELER, bool SPLIT_OUT>
__global__ __launch_bounds__(256, 2) void mfma_gemm_kernel(
        const short* __restrict__ Ah, const short* __restrict__ Al,
        const short* __restrict__ Bh, const short* __restrict__ Bl,
        short* __restrict__ Oh, short* __restrict__ Ol, __half* __restrict__ O16,
        int M,
        const float* __restrict__ al, const float* __restrict__ ar,
        float* __restrict__ el, float* __restrict__ er) {
    // double-buffered staging: [2][128 rows][32 k] shorts = 8 KB per buffer
    __shared__ __align__(16) short As_h[2][128 * 32];
    __shared__ __align__(16) short As_l[2][128 * 32];
    __shared__ __align__(16) short Bs_h[2][128 * 32];
    __shared__ __align__(16) short Bs_l[2][128 * 32];

    const int tid = threadIdx.x;
    const int row0 = blockIdx.x * 128;
    const int col0 = blockIdx.y * 128;

    const int lane = tid & 63;
    const int lr = lane & 15;
    const int lg = lane >> 4;
    const int wid = tid >> 6;
    const int wm = wid >> 1;
    const int wn = wid & 1;

    // staging geometry: wave w owns tile rows [32w, 32w+32); lane l fetches
    // row +(l>>2), 16B at col (l&3)*8. LDS dest = uniform base + lane*16B.
    const int srow = wid * 32 + (lane >> 2);          // first 16-row group
    const int scol = (lane & 3) * 8;
    const size_t aoff1 = (size_t)(row0 + srow) * K + scol;
    const size_t aoff2 = aoff1 + (size_t)16 * K;
    const size_t boff1 = (size_t)(col0 + srow) * K + scol;
    const size_t boff2 = boff1 + (size_t)16 * K;
    const int lbase1 = (wid * 32) * 32;               // shorts
    const int lbase2 = (wid * 32 + 16) * 32;

    auto stage = [&](int buf, int k0) {
        gload16(Ah + aoff1 + k0, &As_h[buf][lbase1]);
        gload16(Ah + aoff2 + k0, &As_h[buf][lbase2]);
        gload16(Al + aoff1 + k0, &As_l[buf][lbase1]);
        gload16(Al + aoff2 + k0, &As_l[buf][lbase2]);
        gload16(Bh + boff1 + k0, &Bs_h[buf][lbase1]);
        gload16(Bh + boff2 + k0, &Bs_h[buf][lbase2]);
        gload16(Bl + boff1 + k0, &Bs_l[buf][lbase1]);
        gload16(Bl + boff2 + k0, &Bs_l[buf][lbase2]);
    };

    f32x4 acc[4][4];
#pragma unroll
    for (int i = 0; i < 4; ++i)
#pragma unroll
        for (int j = 0; j < 4; ++j) acc[i][j] = (f32x4){0.f, 0.f, 0.f, 0.f};

    constexpr int NT = K / 32;
    stage(0, 0);
    __syncthreads();

    int cur = 0;
#pragma unroll
    for (int t = 0; t < NT; ++t) {
        if (t + 1 < NT) stage(cur ^ 1, (t + 1) * 32);

        bf16x8 ah[4], av[4], bh[4], bv[4];
#pragma unroll
        for (int q = 0; q < 4; ++q) {
            int arow = (wm * 64 + q * 16 + lr) * 32 + lg * 8;
            int brow = (wn * 64 + q * 16 + lr) * 32 + lg * 8;
            ah[q] = *reinterpret_cast<const bf16x8*>(&As_h[cur][arow]);
            av[q] = *reinterpret_cast<const bf16x8*>(&As_l[cur][arow]);
            bh[q] = *reinterpret_cast<const bf16x8*>(&Bs_h[cur][brow]);
            bv[q] = *reinterpret_cast<const bf16x8*>(&Bs_l[cur][brow]);
        }
#pragma unroll
        for (int mt = 0; mt < 4; ++mt)
#pragma unroll
            for (int nt = 0; nt < 4; ++nt) {
                acc[mt][nt] = __builtin_amdgcn_mfma_f32_16x16x32_bf16(ah[mt], bh[nt], acc[mt][nt], 0, 0, 0);
                acc[mt][nt] = __builtin_amdgcn_mfma_f32_16x16x32_bf16(ah[mt], bv[nt], acc[mt][nt], 0, 0, 0);
                acc[mt][nt] = __builtin_amdgcn_mfma_f32_16x16x32_bf16(av[mt], bh[nt], acc[mt][nt], 0, 0, 0);
            }
        __syncthreads();   // drains vmcnt (next-tile stage) + lgkm; one barrier/iter
        cur ^= 1;
    }

    const int head = blockIdx.y * 2 + wn;
    float alv[4], arv[4];
    if (ELER) {
#pragma unroll
        for (int nt = 0; nt < 4; ++nt) {
            alv[nt] = al[head * 64 + nt * 16 + lr];
            arv[nt] = ar[head * 64 + nt * 16 + lr];
        }
    }
#pragma unroll
    for (int mt = 0; mt < 4; ++mt) {
#pragma unroll
        for (int r = 0; r < 4; ++r) {
            int row = row0 + wm * 64 + mt * 16 + lg * 4 + r;
            bool valid = row < M;
            float sl = 0.f, sr_ = 0.f;
#pragma unroll
            for (int nt = 0; nt < 4; ++nt) {
                float v = acc[mt][nt][r];
                if (TANH) v = fast_tanh(v);
                if (valid) {
                    size_t ci = (size_t)row * 256 + col0 + wn * 64 + nt * 16 + lr;
                    if (SPLIT_OUT) {
                        short hh, ll;
                        split2(v, hh, ll);
                        Oh[ci] = hh;
                        Ol[ci] = ll;
                    } else {
                        O16[ci] = __float2half(v);
                    }
                }
                if (ELER) { sl = fmaf(v, alv[nt], sl); sr_ = fmaf(v, arv[nt], sr_); }
            }
            if (ELER) {
#pragma unroll
                for (int mask = 1; mask < 16; mask <<= 1) {
                    sl  += __shfl_xor(sl, mask, 16);
                    sr_ += __shfl_xor(sr_, mask, 16);
                }
                if (valid && lr == 0) {
                    el[row * 4 + head] = sl;
                    er[row * 4 + head] = sr_;
                }
            }
        }
    }
}

// ---------------- CSR build ------------------------------------------------
__global__ void count_deg_kernel(const int* __restrict__ dst, int* __restrict__ deg, int E) {
    int i = blockIdx.x * blockDim.x + threadIdx.x;
    if (i < E) atomicAdd(&deg[dst[i]], 1);
}

__global__ __launch_bounds__(1024) void scan_kernel(const int* __restrict__ deg,
                                                    int* __restrict__ offs,
                                                    int* __restrict__ cursor, int n) {
    __shared__ int wsum[16];
    const int tid = threadIdx.x, lane = tid & 63, wv = tid >> 6;
    int carry = 0;
    for (int base = 0; base < n; base += 4096) {
        int i = base + tid * 4;
        int v0 = 0, v1 = 0, v2 = 0, v3 = 0;
        if (i + 3 < n) {
            int4 q = *reinterpret_cast<const int4*>(&deg[i]);
            v0 = q.x; v1 = q.y; v2 = q.z; v3 = q.w;
        } else if (i < n) {
            v0 = deg[i];
            if (i + 1 < n) v1 = deg[i + 1];
            if (i + 2 < n) v2 = deg[i + 2];
        }
        int s = v0 + v1 + v2 + v3;
        int incl = s;
#pragma unroll
        for (int d = 1; d < 64; d <<= 1) {
            int t = __shfl_up(incl, d, 64);
            if (lane >= d) incl += t;
        }
        if (lane == 63) wsum[wv] = incl;
        __syncthreads();
        int woff = 0, tot = 0;
#pragma unroll
        for (int w2 = 0; w2 < 16; ++w2) {
            int x = wsum[w2];
            if (w2 < wv) woff += x;
            tot += x;
        }
        int excl = carry + woff + incl - s;
        if (i < n) {
            int p0 = excl, p1 = p0 + v0, p2 = p1 + v1, p3 = p2 + v2;
            offs[i] = p0; cursor[i] = p0;
            if (i + 1 < n) { offs[i + 1] = p1; cursor[i + 1] = p1; }
            if (i + 2 < n) { offs[i + 2] = p2; cursor[i + 2] = p2; }
            if (i + 3 < n) { offs[i + 3] = p3; cursor[i + 3] = p3; }
        }
        carry += tot;
        __syncthreads();
    }
    if (tid == 0) offs[n] = carry;
}

__global__ void fill_csr_kernel(const int* __restrict__ src, const int* __restrict__ dst,
                                int* __restrict__ cursor, int* __restrict__ srcs_sorted,
                                int* __restrict__ dsts_sorted, int E) {
    int i = blockIdx.x * blockDim.x + threadIdx.x;
    if (i < E) {
        int d = dst[i];
        int pos = atomicAdd(&cursor[d], 1);
        srcs_sorted[pos] = src[i];
        dsts_sorted[pos] = d;
    }
}

// ---------------- edge weights: w[pos] = exp(leaky(el[src] + er[dst])) -----
__global__ __launch_bounds__(256) void edge_w_kernel(const int* __restrict__ srcs,
                                                     const int* __restrict__ dsts,
                                                     const float* __restrict__ el,
                                                     const float* __restrict__ er,
                                                     float4* __restrict__ w, int E) {
    int i = blockIdx.x * 256 + threadIdx.x;
    if (i >= E) return;
    int s = srcs[i], d = dsts[i];
    const float4 a = *reinterpret_cast<const float4*>(&el[(size_t)s * 4]);
    const float4 b = *reinterpret_cast<const float4*>(&er[(size_t)d * 4]);
    float4 o;
    o.x = __expf(leaky02(a.x + b.x));
    o.y = __expf(leaky02(a.y + b.y));
    o.z = __expf(leaky02(a.z + b.z));
    o.w = __expf(leaky02(a.w + b.w));
    w[i] = o;
}

// ---------------- GAT aggregation: wave/node, fp16 rows, precomputed w -----
template<bool FINAL>
__global__ __launch_bounds__(256) void gat_agg_kernel(const __half* __restrict__ feat,
                                                      const float4* __restrict__ wq,
                                                      const int* __restrict__ srcs,
                                                      const int* __restrict__ offs,
                                                      const float* __restrict__ bias,
                                                      float* __restrict__ out,
                                                      short* __restrict__ Gh,
                                                      short* __restrict__ Gl, int N) {
    const int tid = threadIdx.x;
    const int w = tid >> 6, l = tid & 63;
    const int n = blockIdx.x * 4 + w;
    if (n >= N) return;
    const int h = l >> 4;
    const int begin = offs[n];
    const int deg = offs[n + 1] - begin;
    const __half* fbase = feat + (size_t)l * 4;
    const float4 zero4 = make_float4(0.f, 0.f, 0.f, 0.f);

    float4 acc = zero4;
    float z = 0.f;

    for (int j = 0; j < deg; j += 8) {
        const int rem = deg - j;
        const int nb = __builtin_amdgcn_readfirstlane(begin + j);
        const int s0 = srcs[nb + 0];
        const int s1 = (rem > 1) ? srcs[nb + 1] : 0;
        const int s2 = (rem > 2) ? srcs[nb + 2] : 0;
        const int s3 = (rem > 3) ? srcs[nb + 3] : 0;
        const int s4 = (rem > 4) ? srcs[nb + 4] : 0;
        const int s5 = (rem > 5) ? srcs[nb + 5] : 0;
        const int s6 = (rem > 6) ? srcs[nb + 6] : 0;
        const int s7 = (rem > 7) ? srcs[nb + 7] : 0;
        const float4 w0 = wq[nb + 0];
        const float4 w1 = (rem > 1) ? wq[nb + 1] : zero4;
        const float4 w2 = (rem > 2) ? wq[nb + 2] : zero4;
        const float4 w3 = (rem > 3) ? wq[nb + 3] : zero4;
        const float4 w4 = (rem > 4) ? wq[nb + 4] : zero4;
        const float4 w5 = (rem > 5) ? wq[nb + 5] : zero4;
        const float4 w6 = (rem > 6) ? wq[nb + 6] : zero4;
        const float4 w7 = (rem > 7) ? wq[nb + 7] : zero4;
        const uint2 u0 = *reinterpret_cast<const uint2*>(fbase + (size_t)s0 * 256);
        const uint2 u1 = *reinterpret_cast<const uint2*>(fbase + (size_t)s1 * 256);
        const uint2 u2 = *reinterpret_cast<const uint2*>(fbase + (size_t)s2 * 256);
        const uint2 u3 = *reinterpret_cast<const uint2*>(fbase + (size_t)s3 * 256);
        const uint2 u4 = *reinterpret_cast<const uint2*>(fbase + (size_t)s4 * 256);
        const uint2 u5 = *reinterpret_cast<const uint2*>(fbase + (size_t)s5 * 256);
        const uint2 u6 = *reinterpret_cast<const uint2*>(fbase + (size_t)s6 * 256);
        const uint2 u7 = *reinterpret_cast<const uint2*>(fbase + (size_t)s7 * 256);

        const float e0 = sel_head(w0, h);
        const float e1 = sel_head(w1, h);
        const float e2 = sel_head(w2, h);
        const float e3 = sel_head(w3, h);
        const float e4 = sel_head(w4, h);
        const float e5 = sel_head(w5, h);
        const float e6 = sel_head(w6, h);
        const float e7 = sel_head(w7, h);
        z += ((e0 + e1) + (e2 + e3)) + ((e4 + e5) + (e6 + e7));

        auto fma4 = [&](float e, uint2 u) {
            const __half2* hp = reinterpret_cast<const __half2*>(&u);
            float2 a = __half22float2(hp[0]);
            float2 b = __half22float2(hp[1]);
            acc.x = fmaf(e, a.x, acc.x); acc.y = fmaf(e, a.y, acc.y);
            acc.z = fmaf(e, b.x, acc.z); acc.w = fmaf(e, b.y, acc.w);
        };
        fma4(e0, u0); fma4(e1, u1); fma4(e2, u2); fma4(e3, u3);
        fma4(e4, u4); fma4(e5, u5); fma4(e6, u6); fma4(e7, u7);
    }

    const float rz = (z > 0.f) ? __builtin_amdgcn_rcpf(z) : 0.f;
    const float4 bv = *reinterpret_cast<const float4*>(&bias[l * 4]);
    float4 v;
    v.x = fmaf(acc.x, rz, bv.x);
    v.y = fmaf(acc.y, rz, bv.y);
    v.z = fmaf(acc.z, rz, bv.z);
    v.w = fmaf(acc.w, rz, bv.w);
    v.x = v.x > 0.f ? v.x : expm1f(v.x);
    v.y = v.y > 0.f ? v.y : expm1f(v.y);
    v.z = v.z > 0.f ? v.z : expm1f(v.z);
    v.w = v.w > 0.f ? v.w : expm1f(v.w);

    if (!FINAL) {
        short4 hh, ll;
        split2(v.x, hh.x, ll.x);
        split2(v.y, hh.y, ll.y);
        split2(v.z, hh.z, ll.z);
        split2(v.w, hh.w, ll.w);
        *reinterpret_cast<short4*>(&Gh[(size_t)n * 256 + l * 4]) = hh;
        *reinterpret_cast<short4*>(&Gl[(size_t)n * 256 + l * 4]) = ll;
    } else {
        v.x += __shfl_down(v.x, 32, 64); v.y += __shfl_down(v.y, 32, 64);
        v.z += __shfl_down(v.z, 32, 64); v.w += __shfl_down(v.w, 32, 64);
        v.x += __shfl_down(v.x, 16, 64); v.y += __shfl_down(v.y, 16, 64);
        v.z += __shfl_down(v.z, 16, 64); v.w += __shfl_down(v.w, 16, 64);
        if (l < 16) {
            float4 o;
            o.x = 0.25f * v.x; o.y = 0.25f * v.y; o.z = 0.25f * v.z; o.w = 0.25f * v.w;
            *reinterpret_cast<float4*>(&out[(size_t)n * 64 + l * 4]) = o;
        }
    }
}

// ---------------------------------------------------------------------------
extern "C" void kernel_launch(void* const* d_in, const int* in_sizes, int n_in,
                              void* d_out, int out_size, void* d_ws, size_t ws_size,
                              hipStream_t stream) {
    const float* x_feat = (const float*)d_in[0];
    const float* W_fc   = (const float*)d_in[1];
    const float* W1     = (const float*)d_in[2];
    const float* al1    = (const float*)d_in[3];
    const float* ar1    = (const float*)d_in[4];
    const float* b1     = (const float*)d_in[5];
    const float* W2     = (const float*)d_in[6];
    const float* al2    = (const float*)d_in[7];
    const float* ar2    = (const float*)d_in[8];
    const float* b2     = (const float*)d_in[9];
    const int*   src    = (const int*)d_in[10];
    const int*   dst    = (const int*)d_in[11];
    float* out = (float*)d_out;

    const int N = in_sizes[0] / 128;   // 50000
    const int E = in_sizes[10];        // 800000
    const int NB = (N + 127) / 128;    // 391
    const int M_pad = NB * 128;        // 50048

    char* ws = (char*)d_ws;
    size_t off = 0;
    auto alloc = [&](size_t bytes) -> void* {
        off = (off + 255) & ~(size_t)255;
        void* p = ws + off;
        off += bytes;
        return p;
    };
    short* Xh   = (short*)alloc((size_t)M_pad * 128 * 2);
    short* Xl   = (short*)alloc((size_t)M_pad * 128 * 2);
    short* Hh   = (short*)alloc((size_t)M_pad * 256 * 2);  // h tables; reused as g1
    short* Hl   = (short*)alloc((size_t)M_pad * 256 * 2);
    __half* f16 = (__half*)alloc((size_t)M_pad * 256 * 2); // feat1/feat2 gather table
    float* el   = (float*)alloc((size_t)N * 4 * 4);
    float* er   = (float*)alloc((size_t)N * 4 * 4);
    int* deg    = (int*)alloc((size_t)N * 4);
    int* offs   = (int*)alloc((size_t)(N + 4) * 4);
    int* cursor = (int*)alloc((size_t)N * 4);
    int* srcs_sorted = (int*)alloc((size_t)(E + 8) * 4);
    int* dsts_sorted = (int*)alloc((size_t)(E + 8) * 4);
    float4* wq  = (float4*)alloc((size_t)(E + 8) * 16);
    short* Bfc_h = (short*)alloc((size_t)256 * 128 * 2);
    short* Bfc_l = (short*)alloc((size_t)256 * 128 * 2);
    short* B1_h  = (short*)alloc((size_t)256 * 256 * 2);
    short* B1_l  = (short*)alloc((size_t)256 * 256 * 2);
    short* B2_h  = (short*)alloc((size_t)256 * 256 * 2);
    short* B2_l  = (short*)alloc((size_t)256 * 256 * 2);

    const int eb = (E + 255) / 256;
    dim3 ggrid(NB, 2);
    const int agrid = (N + 3) / 4;

    // CSR build (by dst)
    hipMemsetAsync(deg, 0, (size_t)N * 4, stream);
    count_deg_kernel<<<eb, 256, 0, stream>>>(dst, deg, E);
    scan_kernel<<<1, 1024, 0, stream>>>(deg, offs, cursor, N);
    fill_csr_kernel<<<eb, 256, 0, stream>>>(src, dst, cursor, srcs_sorted, dsts_sorted, E);

    // operand pre-splits
    wsplit3_kernel<<<(128 * 256 + 2 * 256 * 256 + 255) / 256, 256, 0, stream>>>(
        W_fc, Bfc_h, Bfc_l, W1, B1_h, B1_l, W2, B2_h, B2_l);
    xsplit_kernel<<<(N * 128 + 255) / 256, 256, 0, stream>>>(x_feat, Xh, Xl, N * 128);

    // h = tanh(x @ W_fc) -> split bf16 tables (GEMM2's A)
    mfma_gemm_kernel<128, true, false, true><<<ggrid, 256, 0, stream>>>(
        Xh, Xl, Bfc_h, Bfc_l, Hh, Hl, nullptr, N, nullptr, nullptr, nullptr, nullptr);
    // feat1 = h @ W1 -> fp16 gather table (+ el/er)
    mfma_gemm_kernel<256, false, true, false><<<ggrid, 256, 0, stream>>>(
        Hh, Hl, B1_h, B1_l, nullptr, nullptr, f16, N, al1, ar1, el, er);
    // edge weights for layer 1
    edge_w_kernel<<<eb, 256, 0, stream>>>(srcs_sorted, dsts_sorted, el, er, wq, E);
    // g1 -> split bf16 tables (reuse Hh/Hl; GEMM3's A)
    gat_agg_kernel<false><<<agrid, 256, 0, stream>>>(
        f16, wq, srcs_sorted, offs, b1, nullptr, Hh, Hl, N);
    // feat2 = g1 @ W2 -> fp16 gather table (+ el/er)
    mfma_gemm_kernel<256, false, true, false><<<ggrid, 256, 0, stream>>>(
        Hh, Hl, B2_h, B2_l, nullptr, nullptr, f16, N, al2, ar2, el, er);
    // edge weights for layer 2
    edge_w_kernel<<<eb, 256, 0, stream>>>(srcs_sorted, dsts_sorted, el, er, wq, E);
    // final aggregation + head mean -> out
    gat_agg_kernel<true><<<agrid, 256, 0, stream>>>(
        f16, wq, srcs_sorted, offs, b2, out, nullptr, nullptr, N);
}

// Round 12
// 455.625 us; speedup vs baseline: 1.0436x; 1.0436x over previous
//
#include <hip/hip_runtime.h>
#include <hip/hip_bf16.h>
#include <hip/hip_fp16.h>
#include <math.h>

// ---------------------------------------------------------------------------
// HomoGAT on MI355X. 9-dispatch pipeline:
//   prep -> count_deg -> scan -> fill_csr -> GEMM1 -> GEMM2 -> agg1
//        -> GEMM3 -> agg2
//  - GEMMs: split-precision bf16 MFMA, pre-split operand tables,
//    global_load_lds double-buffered k-loop (R10 structure).
//  - agg: wave-per-node, fp16 feat gather (line-rate bound), INLINE edge
//    weights (el gathers are L2-resident broadcasts) -> no edge_w kernels.
// (Resubmission: previous bench hit container failure.)
// ---------------------------------------------------------------------------

typedef __attribute__((ext_vector_type(8))) short bf16x8;
typedef __attribute__((ext_vector_type(4))) float f32x4;

typedef const __attribute__((address_space(1))) char gas_char;
typedef __attribute__((address_space(3))) char las_char;

__device__ __forceinline__ void gload16(const void* g, void* l) {
    __builtin_amdgcn_global_load_lds((gas_char*)g, (las_char*)l, 16, 0, 0);
}

__device__ __forceinline__ void split2(float v, short& h, short& l) {
    __hip_bfloat16 bh = __float2bfloat16(v);
    float r = v - __bfloat162float(bh);
    __hip_bfloat16 bl = __float2bfloat16(r);
    h = *reinterpret_cast<short*>(&bh);
    l = *reinterpret_cast<short*>(&bl);
}

__device__ __forceinline__ float fast_tanh(float x) {
    x = fminf(fmaxf(x, -15.f), 15.f);
    float e = __expf(2.f * x);
    return (e - 1.f) * __builtin_amdgcn_rcpf(e + 1.f);
}

__device__ __forceinline__ float leaky02(float x) { return x > 0.f ? x : 0.2f * x; }

__device__ __forceinline__ float sel_head(float4 q, int h) {
    float lo = (h & 1) ? q.y : q.x;
    float hi = (h & 1) ? q.w : q.z;
    return (h & 2) ? hi : lo;
}

// ---------------- prep: xsplit (4/thread) + wsplit3 + zero deg -------------
__global__ __launch_bounds__(256) void prep_kernel(
        const float* __restrict__ X, short* __restrict__ Xh, short* __restrict__ Xl,
        int xquads,
        const float* __restrict__ W0, short* __restrict__ B0h, short* __restrict__ B0l,
        const float* __restrict__ W1, short* __restrict__ B1h, short* __restrict__ B1l,
        const float* __restrict__ W2, short* __restrict__ B2h, short* __restrict__ B2l,
        int* __restrict__ deg, int N) {
    int gid = blockIdx.x * 256 + threadIdx.x;
    if (gid < N) deg[gid] = 0;
    if (gid < xquads) {
        float4 v = reinterpret_cast<const float4*>(X)[gid];
        short4 h, l;
        split2(v.x, h.x, l.x);
        split2(v.y, h.y, l.y);
        split2(v.z, h.z, l.z);
        split2(v.w, h.w, l.w);
        reinterpret_cast<short4*>(Xh)[gid] = h;
        reinterpret_cast<short4*>(Xl)[gid] = l;
        return;
    }
    int rel = gid - xquads;
    const float* W;
    short *Bh, *Bl;
    int K;
    if (rel < 128 * 256) {
        W = W0; Bh = B0h; Bl = B0l; K = 128;
    } else if (rel < 128 * 256 + 256 * 256) {
        W = W1; Bh = B1h; Bl = B1l; K = 256; rel -= 128 * 256;
    } else if (rel < 128 * 256 + 2 * 256 * 256) {
        W = W2; Bh = B2h; Bl = B2l; K = 256; rel -= 128 * 256 + 256 * 256;
    } else {
        return;
    }
    int k = rel >> 8, n = rel & 255;
    short h, l;
    split2(W[rel], h, l);
    Bh[n * K + k] = h;
    Bl[n * K + k] = l;
}

// ---------------- MFMA GEMM: C[M,256] = A[M,K] @ B[K,256] ------------------
template<int K, bool TANH, bool ELER, bool SPLIT_OUT>
__global__ __launch_bounds__(256, 2) void mfma_gemm_kernel(
        const short* __restrict__ Ah, const short* __restrict__ Al,
        const short* __restrict__ Bh, const short* __restrict__ Bl,
        short* __restrict__ Oh, short* __restrict__ Ol, __half* __restrict__ O16,
        int M,
        const float* __restrict__ al, const float* __restrict__ ar,
        float* __restrict__ el, float* __restrict__ er) {
    __shared__ __align__(16) short As_h[2][128 * 32];
    __shared__ __align__(16) short As_l[2][128 * 32];
    __shared__ __align__(16) short Bs_h[2][128 * 32];
    __shared__ __align__(16) short Bs_l[2][128 * 32];

    const int tid = threadIdx.x;
    const int row0 = blockIdx.x * 128;
    const int col0 = blockIdx.y * 128;

    const int lane = tid & 63;
    const int lr = lane & 15;
    const int lg = lane >> 4;
    const int wid = tid >> 6;
    const int wm = wid >> 1;
    const int wn = wid & 1;

    const int srow = wid * 32 + (lane >> 2);
    const int scol = (lane & 3) * 8;
    const size_t aoff1 = (size_t)(row0 + srow) * K + scol;
    const size_t aoff2 = aoff1 + (size_t)16 * K;
    const size_t boff1 = (size_t)(col0 + srow) * K + scol;
    const size_t boff2 = boff1 + (size_t)16 * K;
    const int lbase1 = (wid * 32) * 32;
    const int lbase2 = (wid * 32 + 16) * 32;

    auto stage = [&](int buf, int k0) {
        gload16(Ah + aoff1 + k0, &As_h[buf][lbase1]);
        gload16(Ah + aoff2 + k0, &As_h[buf][lbase2]);
        gload16(Al + aoff1 + k0, &As_l[buf][lbase1]);
        gload16(Al + aoff2 + k0, &As_l[buf][lbase2]);
        gload16(Bh + boff1 + k0, &Bs_h[buf][lbase1]);
        gload16(Bh + boff2 + k0, &Bs_h[buf][lbase2]);
        gload16(Bl + boff1 + k0, &Bs_l[buf][lbase1]);
        gload16(Bl + boff2 + k0, &Bs_l[buf][lbase2]);
    };

    f32x4 acc[4][4];
#pragma unroll
    for (int i = 0; i < 4; ++i)
#pragma unroll
        for (int j = 0; j < 4; ++j) acc[i][j] = (f32x4){0.f, 0.f, 0.f, 0.f};

    constexpr int NT = K / 32;
    stage(0, 0);
    __syncthreads();

    int cur = 0;
#pragma unroll
    for (int t = 0; t < NT; ++t) {
        if (t + 1 < NT) stage(cur ^ 1, (t + 1) * 32);

        bf16x8 ah[4], av[4], bh[4], bv[4];
#pragma unroll
        for (int q = 0; q < 4; ++q) {
            int arow = (wm * 64 + q * 16 + lr) * 32 + lg * 8;
            int brow = (wn * 64 + q * 16 + lr) * 32 + lg * 8;
            ah[q] = *reinterpret_cast<const bf16x8*>(&As_h[cur][arow]);
            av[q] = *reinterpret_cast<const bf16x8*>(&As_l[cur][arow]);
            bh[q] = *reinterpret_cast<const bf16x8*>(&Bs_h[cur][brow]);
            bv[q] = *reinterpret_cast<const bf16x8*>(&Bs_l[cur][brow]);
        }
#pragma unroll
        for (int mt = 0; mt < 4; ++mt)
#pragma unroll
            for (int nt = 0; nt < 4; ++nt) {
                acc[mt][nt] = __builtin_amdgcn_mfma_f32_16x16x32_bf16(ah[mt], bh[nt], acc[mt][nt], 0, 0, 0);
                acc[mt][nt] = __builtin_amdgcn_mfma_f32_16x16x32_bf16(ah[mt], bv[nt], acc[mt][nt], 0, 0, 0);
                acc[mt][nt] = __builtin_amdgcn_mfma_f32_16x16x32_bf16(av[mt], bh[nt], acc[mt][nt], 0, 0, 0);
            }
        __syncthreads();
        cur ^= 1;
    }

    const int head = blockIdx.y * 2 + wn;
    float alv[4], arv[4];
    if (ELER) {
#pragma unroll
        for (int nt = 0; nt < 4; ++nt) {
            alv[nt] = al[head * 64 + nt * 16 + lr];
            arv[nt] = ar[head * 64 + nt * 16 + lr];
        }
    }
#pragma unroll
    for (int mt = 0; mt < 4; ++mt) {
#pragma unroll
        for (int r = 0; r < 4; ++r) {
            int row = row0 + wm * 64 + mt * 16 + lg * 4 + r;
            bool valid = row < M;
            float sl = 0.f, sr_ = 0.f;
#pragma unroll
            for (int nt = 0; nt < 4; ++nt) {
                float v = acc[mt][nt][r];
                if (TANH) v = fast_tanh(v);
                if (valid) {
                    size_t ci = (size_t)row * 256 + col0 + wn * 64 + nt * 16 + lr;
                    if (SPLIT_OUT) {
                        short hh, ll;
                        split2(v, hh, ll);
                        Oh[ci] = hh;
                        Ol[ci] = ll;
                    } else {
                        O16[ci] = __float2half(v);
                    }
                }
                if (ELER) { sl = fmaf(v, alv[nt], sl); sr_ = fmaf(v, arv[nt], sr_); }
            }
            if (ELER) {
#pragma unroll
                for (int mask = 1; mask < 16; mask <<= 1) {
                    sl  += __shfl_xor(sl, mask, 16);
                    sr_ += __shfl_xor(sr_, mask, 16);
                }
                if (valid && lr == 0) {
                    el[row * 4 + head] = sl;
                    er[row * 4 + head] = sr_;
                }
            }
        }
    }
}

// ---------------- CSR build ------------------------------------------------
__global__ void count_deg_kernel(const int* __restrict__ dst, int* __restrict__ deg, int E) {
    int i = blockIdx.x * blockDim.x + threadIdx.x;
    if (i < E) atomicAdd(&deg[dst[i]], 1);
}

__global__ __launch_bounds__(1024) void scan_kernel(const int* __restrict__ deg,
                                                    int* __restrict__ offs,
                                                    int* __restrict__ cursor, int n) {
    __shared__ int wsum[16];
    const int tid = threadIdx.x, lane = tid & 63, wv = tid >> 6;
    int carry = 0;
    for (int base = 0; base < n; base += 4096) {
        int i = base + tid * 4;
        int v0 = 0, v1 = 0, v2 = 0, v3 = 0;
        if (i + 3 < n) {
            int4 q = *reinterpret_cast<const int4*>(&deg[i]);
            v0 = q.x; v1 = q.y; v2 = q.z; v3 = q.w;
        } else if (i < n) {
            v0 = deg[i];
            if (i + 1 < n) v1 = deg[i + 1];
            if (i + 2 < n) v2 = deg[i + 2];
        }
        int s = v0 + v1 + v2 + v3;
        int incl = s;
#pragma unroll
        for (int d = 1; d < 64; d <<= 1) {
            int t = __shfl_up(incl, d, 64);
            if (lane >= d) incl += t;
        }
        if (lane == 63) wsum[wv] = incl;
        __syncthreads();
        int woff = 0, tot = 0;
#pragma unroll
        for (int w2 = 0; w2 < 16; ++w2) {
            int x = wsum[w2];
            if (w2 < wv) woff += x;
            tot += x;
        }
        int excl = carry + woff + incl - s;
        if (i < n) {
            int p0 = excl, p1 = p0 + v0, p2 = p1 + v1, p3 = p2 + v2;
            offs[i] = p0; cursor[i] = p0;
            if (i + 1 < n) { offs[i + 1] = p1; cursor[i + 1] = p1; }
            if (i + 2 < n) { offs[i + 2] = p2; cursor[i + 2] = p2; }
            if (i + 3 < n) { offs[i + 3] = p3; cursor[i + 3] = p3; }
        }
        carry += tot;
        __syncthreads();
    }
    if (tid == 0) offs[n] = carry;
}

__global__ void fill_csr_kernel(const int* __restrict__ src, const int* __restrict__ dst,
                                int* __restrict__ cursor, int* __restrict__ srcs_sorted, int E) {
    int i = blockIdx.x * blockDim.x + threadIdx.x;
    if (i < E) {
        int d = dst[i];
        int pos = atomicAdd(&cursor[d], 1);
        srcs_sorted[pos] = src[i];
    }
}

// ---------------- GAT aggregation: wave/node, fp16 rows, inline weights ----
// w_e = exp(leaky(el[s]+er[n])) computed in-loop; el loads are wave-uniform
// float4 broadcasts from the L2-resident el table (no wq pass, no edge_w).
template<bool FINAL>
__global__ __launch_bounds__(256) void gat_agg_kernel(const __half* __restrict__ feat,
                                                      const float* __restrict__ el,
                                                      const float* __restrict__ er,
                                                      const int* __restrict__ srcs,
                                                      const int* __restrict__ offs,
                                                      const float* __restrict__ bias,
                                                      float* __restrict__ out,
                                                      short* __restrict__ Gh,
                                                      short* __restrict__ Gl, int N) {
    const int tid = threadIdx.x;
    const int w = tid >> 6, l = tid & 63;
    const int n = blockIdx.x * 4 + w;
    if (n >= N) return;
    const int h = l >> 4;
    const int begin = offs[n];
    const int deg = offs[n + 1] - begin;
    const float erh = er[n * 4 + h];
    const __half* fbase = feat + (size_t)l * 4;

    float4 acc = make_float4(0.f, 0.f, 0.f, 0.f);
    float z = 0.f;

    for (int j = 0; j < deg; j += 8) {
        const int rem = deg - j;
        const int nb = __builtin_amdgcn_readfirstlane(begin + j);
        const int s0 = srcs[nb + 0];
        const int s1 = (rem > 1) ? srcs[nb + 1] : 0;
        const int s2 = (rem > 2) ? srcs[nb + 2] : 0;
        const int s3 = (rem > 3) ? srcs[nb + 3] : 0;
        const int s4 = (rem > 4) ? srcs[nb + 4] : 0;
        const int s5 = (rem > 5) ? srcs[nb + 5] : 0;
        const int s6 = (rem > 6) ? srcs[nb + 6] : 0;
        const int s7 = (rem > 7) ? srcs[nb + 7] : 0;
        // wave-uniform el rows (broadcast lines, L2-resident table)
        const float4 q0 = *reinterpret_cast<const float4*>(&el[(size_t)s0 * 4]);
        const float4 q1 = *reinterpret_cast<const float4*>(&el[(size_t)s1 * 4]);
        const float4 q2 = *reinterpret_cast<const float4*>(&el[(size_t)s2 * 4]);
        const float4 q3 = *reinterpret_cast<const float4*>(&el[(size_t)s3 * 4]);
        const float4 q4 = *reinterpret_cast<const float4*>(&el[(size_t)s4 * 4]);
        const float4 q5 = *reinterpret_cast<const float4*>(&el[(size_t)s5 * 4]);
        const float4 q6 = *reinterpret_cast<const float4*>(&el[(size_t)s6 * 4]);
        const float4 q7 = *reinterpret_cast<const float4*>(&el[(size_t)s7 * 4]);
        // 8 independent fp16 feat-row loads (the only scattered stream)
        const uint2 u0 = *reinterpret_cast<const uint2*>(fbase + (size_t)s0 * 256);
        const uint2 u1 = *reinterpret_cast<const uint2*>(fbase + (size_t)s1 * 256);
        const uint2 u2 = *reinterpret_cast<const uint2*>(fbase + (size_t)s2 * 256);
        const uint2 u3 = *reinterpret_cast<const uint2*>(fbase + (size_t)s3 * 256);
        const uint2 u4 = *reinterpret_cast<const uint2*>(fbase + (size_t)s4 * 256);
        const uint2 u5 = *reinterpret_cast<const uint2*>(fbase + (size_t)s5 * 256);
        const uint2 u6 = *reinterpret_cast<const uint2*>(fbase + (size_t)s6 * 256);
        const uint2 u7 = *reinterpret_cast<const uint2*>(fbase + (size_t)s7 * 256);

        const float e0 = __expf(leaky02(sel_head(q0, h) + erh));
        const float e1 = (rem > 1) ? __expf(leaky02(sel_head(q1, h) + erh)) : 0.f;
        const float e2 = (rem > 2) ? __expf(leaky02(sel_head(q2, h) + erh)) : 0.f;
        const float e3 = (rem > 3) ? __expf(leaky02(sel_head(q3, h) + erh)) : 0.f;
        const float e4 = (rem > 4) ? __expf(leaky02(sel_head(q4, h) + erh)) : 0.f;
        const float e5 = (rem > 5) ? __expf(leaky02(sel_head(q5, h) + erh)) : 0.f;
        const float e6 = (rem > 6) ? __expf(leaky02(sel_head(q6, h) + erh)) : 0.f;
        const float e7 = (rem > 7) ? __expf(leaky02(sel_head(q7, h) + erh)) : 0.f;
        z += ((e0 + e1) + (e2 + e3)) + ((e4 + e5) + (e6 + e7));

        auto fma4 = [&](float e, uint2 u) {
            const __half2* hp = reinterpret_cast<const __half2*>(&u);
            float2 a = __half22float2(hp[0]);
            float2 b = __half22float2(hp[1]);
            acc.x = fmaf(e, a.x, acc.x); acc.y = fmaf(e, a.y, acc.y);
            acc.z = fmaf(e, b.x, acc.z); acc.w = fmaf(e, b.y, acc.w);
        };
        fma4(e0, u0); fma4(e1, u1); fma4(e2, u2); fma4(e3, u3);
        fma4(e4, u4); fma4(e5, u5); fma4(e6, u6); fma4(e7, u7);
    }

    const float rz = (z > 0.f) ? __builtin_amdgcn_rcpf(z) : 0.f;
    const float4 bv = *reinterpret_cast<const float4*>(&bias[l * 4]);
    float4 v;
    v.x = fmaf(acc.x, rz, bv.x);
    v.y = fmaf(acc.y, rz, bv.y);
    v.z = fmaf(acc.z, rz, bv.z);
    v.w = fmaf(acc.w, rz, bv.w);
    v.x = v.x > 0.f ? v.x : expm1f(v.x);
    v.y = v.y > 0.f ? v.y : expm1f(v.y);
    v.z = v.z > 0.f ? v.z : expm1f(v.z);
    v.w = v.w > 0.f ? v.w : expm1f(v.w);

    if (!FINAL) {
        short4 hh, ll;
        split2(v.x, hh.x, ll.x);
        split2(v.y, hh.y, ll.y);
        split2(v.z, hh.z, ll.z);
        split2(v.w, hh.w, ll.w);
        *reinterpret_cast<short4*>(&Gh[(size_t)n * 256 + l * 4]) = hh;
        *reinterpret_cast<short4*>(&Gl[(size_t)n * 256 + l * 4]) = ll;
    } else {
        v.x += __shfl_down(v.x, 32, 64); v.y += __shfl_down(v.y, 32, 64);
        v.z += __shfl_down(v.z, 32, 64); v.w += __shfl_down(v.w, 32, 64);
        v.x += __shfl_down(v.x, 16, 64); v.y += __shfl_down(v.y, 16, 64);
        v.z += __shfl_down(v.z, 16, 64); v.w += __shfl_down(v.w, 16, 64);
        if (l < 16) {
            float4 o;
            o.x = 0.25f * v.x; o.y = 0.25f * v.y; o.z = 0.25f * v.z; o.w = 0.25f * v.w;
            *reinterpret_cast<float4*>(&out[(size_t)n * 64 + l * 4]) = o;
        }
    }
}

// ---------------------------------------------------------------------------
extern "C" void kernel_launch(void* const* d_in, const int* in_sizes, int n_in,
                              void* d_out, int out_size, void* d_ws, size_t ws_size,
                              hipStream_t stream) {
    const float* x_feat = (const float*)d_in[0];
    const float* W_fc   = (const float*)d_in[1];
    const float* W1     = (const float*)d_in[2];
    const float* al1    = (const float*)d_in[3];
    const float* ar1    = (const float*)d_in[4];
    const float* b1     = (const float*)d_in[5];
    const float* W2     = (const float*)d_in[6];
    const float* al2    = (const float*)d_in[7];
    const float* ar2    = (const float*)d_in[8];
    const float* b2     = (const float*)d_in[9];
    const int*   src    = (const int*)d_in[10];
    const int*   dst    = (const int*)d_in[11];
    float* out = (float*)d_out;

    const int N = in_sizes[0] / 128;   // 50000
    const int E = in_sizes[10];        // 800000
    const int NB = (N + 127) / 128;    // 391
    const int M_pad = NB * 128;        // 50048

    char* ws = (char*)d_ws;
    size_t off = 0;
    auto alloc = [&](size_t bytes) -> void* {
        off = (off + 255) & ~(size_t)255;
        void* p = ws + off;
        off += bytes;
        return p;
    };
    short* Xh   = (short*)alloc((size_t)M_pad * 128 * 2);
    short* Xl   = (short*)alloc((size_t)M_pad * 128 * 2);
    short* Hh   = (short*)alloc((size_t)M_pad * 256 * 2);  // h tables; reused as g1
    short* Hl   = (short*)alloc((size_t)M_pad * 256 * 2);
    __half* f16 = (__half*)alloc((size_t)M_pad * 256 * 2); // feat1/feat2 gather table
    float* el   = (float*)alloc((size_t)N * 4 * 4);
    float* er   = (float*)alloc((size_t)N * 4 * 4);
    int* deg    = (int*)alloc((size_t)N * 4);
    int* offs   = (int*)alloc((size_t)(N + 4) * 4);
    int* cursor = (int*)alloc((size_t)N * 4);
    int* srcs_sorted = (int*)alloc((size_t)(E + 8) * 4);
    short* Bfc_h = (short*)alloc((size_t)256 * 128 * 2);
    short* Bfc_l = (short*)alloc((size_t)256 * 128 * 2);
    short* B1_h  = (short*)alloc((size_t)256 * 256 * 2);
    short* B1_l  = (short*)alloc((size_t)256 * 256 * 2);
    short* B2_h  = (short*)alloc((size_t)256 * 256 * 2);
    short* B2_l  = (short*)alloc((size_t)256 * 256 * 2);

    const int eb = (E + 255) / 256;
    dim3 ggrid(NB, 2);
    const int agrid = (N + 3) / 4;

    const int xquads = N * 128 / 4;                       // 1.6M
    const int prep_threads = xquads + 128 * 256 + 2 * 256 * 256;
    // 1: prep (xsplit + wsplit3 + zero deg)
    prep_kernel<<<(prep_threads + 255) / 256, 256, 0, stream>>>(
        x_feat, Xh, Xl, xquads, W_fc, Bfc_h, Bfc_l, W1, B1_h, B1_l, W2, B2_h, B2_l,
        deg, N);
    // 2-4: CSR build (by dst)
    count_deg_kernel<<<eb, 256, 0, stream>>>(dst, deg, E);
    scan_kernel<<<1, 1024, 0, stream>>>(deg, offs, cursor, N);
    fill_csr_kernel<<<eb, 256, 0, stream>>>(src, dst, cursor, srcs_sorted, E);
    // 5: h = tanh(x @ W_fc) -> split bf16 tables
    mfma_gemm_kernel<128, true, false, true><<<ggrid, 256, 0, stream>>>(
        Xh, Xl, Bfc_h, Bfc_l, Hh, Hl, nullptr, N, nullptr, nullptr, nullptr, nullptr);
    // 6: feat1 = h @ W1 -> fp16 gather table (+ el/er)
    mfma_gemm_kernel<256, false, true, false><<<ggrid, 256, 0, stream>>>(
        Hh, Hl, B1_h, B1_l, nullptr, nullptr, f16, N, al1, ar1, el, er);
    // 7: g1 -> split bf16 tables (reuse Hh/Hl)
    gat_agg_kernel<false><<<agrid, 256, 0, stream>>>(
        f16, el, er, srcs_sorted, offs, b1, nullptr, Hh, Hl, N);
    // 8: feat2 = g1 @ W2 -> fp16 gather table (+ el/er)
    mfma_gemm_kernel<256, false, true, false><<<ggrid, 256, 0, stream>>>(
        Hh, Hl, B2_h, B2_l, nullptr, nullptr, f16, N, al2, ar2, el, er);
    // 9: final aggregation + head mean -> out
    gat_agg_kernel<true><<<agrid, 256, 0, stream>>>(
        f16, el, er, srcs_sorted, offs, b2, out, nullptr, nullptr, N);
}

// Round 13
// 435.410 us; speedup vs baseline: 1.0920x; 1.0464x over previous
//
#include <hip/hip_runtime.h>
#include <hip/hip_bf16.h>
#include <hip/hip_fp16.h>
#include <math.h>

// ---------------------------------------------------------------------------
// HomoGAT on MI355X. 9-dispatch pipeline:
//   prep -> count_deg -> scan -> fill_csr -> GEMM1 -> GEMM2 -> agg1
//        -> GEMM3 -> agg2
//  - GEMMs: split-precision bf16 MFMA, FULL-WIDTH blocks (BN=256, grid.y=1):
//    A-tile staged once (halved A traffic), 512 thr / 8 waves, 48 KB LDS,
//    2 blocks/CU. GEMM1 splits fp32 X in-kernel; GEMM2/3 use bf16 tables
//    via global_load_lds.
//  - agg: wave-per-node, fp16 feat gather, inline edge weights.
// ---------------------------------------------------------------------------

typedef __attribute__((ext_vector_type(8))) short bf16x8;
typedef __attribute__((ext_vector_type(4))) float f32x4;

typedef const __attribute__((address_space(1))) char gas_char;
typedef __attribute__((address_space(3))) char las_char;

__device__ __forceinline__ void gload16(const void* g, void* l) {
    __builtin_amdgcn_global_load_lds((gas_char*)g, (las_char*)l, 16, 0, 0);
}

__device__ __forceinline__ void split2(float v, short& h, short& l) {
    __hip_bfloat16 bh = __float2bfloat16(v);
    float r = v - __bfloat162float(bh);
    __hip_bfloat16 bl = __float2bfloat16(r);
    h = *reinterpret_cast<short*>(&bh);
    l = *reinterpret_cast<short*>(&bl);
}

__device__ __forceinline__ float fast_tanh(float x) {
    x = fminf(fmaxf(x, -15.f), 15.f);
    float e = __expf(2.f * x);
    return (e - 1.f) * __builtin_amdgcn_rcpf(e + 1.f);
}

__device__ __forceinline__ float leaky02(float x) { return x > 0.f ? x : 0.2f * x; }

__device__ __forceinline__ float sel_head(float4 q, int h) {
    float lo = (h & 1) ? q.y : q.x;
    float hi = (h & 1) ? q.w : q.z;
    return (h & 2) ? hi : lo;
}

// ---------------- prep: wsplit3 + zero deg ---------------------------------
__global__ __launch_bounds__(256) void prep_kernel(
        const float* __restrict__ W0, short* __restrict__ B0h, short* __restrict__ B0l,
        const float* __restrict__ W1, short* __restrict__ B1h, short* __restrict__ B1l,
        const float* __restrict__ W2, short* __restrict__ B2h, short* __restrict__ B2l,
        int* __restrict__ deg, int N) {
    int gid = blockIdx.x * 256 + threadIdx.x;
    if (gid < N) deg[gid] = 0;
    int rel = gid;
    const float* W;
    short *Bh, *Bl;
    int K;
    if (rel < 128 * 256) {
        W = W0; Bh = B0h; Bl = B0l; K = 128;
    } else if (rel < 128 * 256 + 256 * 256) {
        W = W1; Bh = B1h; Bl = B1l; K = 256; rel -= 128 * 256;
    } else if (rel < 128 * 256 + 2 * 256 * 256) {
        W = W2; Bh = B2h; Bl = B2l; K = 256; rel -= 128 * 256 + 256 * 256;
    } else {
        return;
    }
    int k = rel >> 8, n = rel & 255;
    short h, l;
    split2(W[rel], h, l);
    Bh[n * K + k] = h;
    Bl[n * K + k] = l;
}

// ---------------- MFMA GEMM: C[M,256] = A[M,K] @ B[K,256], BN=256 ----------
// 512 threads = 8 waves (2 row x 4 col of 64x64). Single-buffered LDS.
// AFP32: A is fp32 (GEMM1), split in-kernel; else pre-split bf16 tables.
template<int K, bool AFP32, bool TANH, bool ELER, bool SPLIT_OUT>
__global__ __launch_bounds__(512, 4) void mfma_gemm_kernel(
        const float* __restrict__ Af,
        const short* __restrict__ Ah, const short* __restrict__ Al,
        const short* __restrict__ Bh, const short* __restrict__ Bl,
        short* __restrict__ Oh, short* __restrict__ Ol, __half* __restrict__ O16,
        int M,
        const float* __restrict__ al, const float* __restrict__ ar,
        float* __restrict__ el, float* __restrict__ er) {
    __shared__ __align__(16) short As_h[128 * 32];   // 8 KB
    __shared__ __align__(16) short As_l[128 * 32];   // 8 KB
    __shared__ __align__(16) short Bs_h[256 * 32];   // 16 KB
    __shared__ __align__(16) short Bs_l[256 * 32];   // 16 KB

    const int tid = threadIdx.x;
    const int row0 = blockIdx.x * 128;
    const int lane = tid & 63;
    const int lr = lane & 15;
    const int lg = lane >> 4;
    const int wid = tid >> 6;      // 0..7
    const int wm = wid >> 2;       // 0..1 (row half)
    const int wn = wid & 3;        // 0..3 (col quarter = head)

    // staging geometry (lane-linear LDS dests for global_load_lds):
    // A: wave w covers rows [16w,16w+16); lane l -> row 16w+(l>>2), col (l&3)*8
    //    dest = &As[w*512] + lane*16B  (l>>2)*64B + (l&3)*16B = l*16B ✓
    const int arow16 = 16 * wid + (lane >> 2);
    const int acol = (lane & 3) * 8;
    // B: wave w covers rows [32w,32w+32) in two 16-row groups
    const int brow32 = 32 * wid + (lane >> 2);

    f32x4 acc[4][4];
#pragma unroll
    for (int i = 0; i < 4; ++i)
#pragma unroll
        for (int j = 0; j < 4; ++j) acc[i][j] = (f32x4){0.f, 0.f, 0.f, 0.f};

    constexpr int NT = K / 32;
#pragma unroll
    for (int t = 0; t < NT; ++t) {
        const int k0 = t * 32;
        // ---- stage A ----
        if (AFP32) {
            const int row = tid >> 2;              // 0..127
            const int c8 = (tid & 3) * 8;
            int g = row0 + row;
            float va[8];
            if (g < M) {
                const float4* ap = reinterpret_cast<const float4*>(&Af[(size_t)g * K + k0 + c8]);
                *reinterpret_cast<float4*>(&va[0]) = ap[0];
                *reinterpret_cast<float4*>(&va[4]) = ap[1];
            } else {
#pragma unroll
                for (int i = 0; i < 8; ++i) va[i] = 0.f;
            }
            short hs[8], ls[8];
#pragma unroll
            for (int i = 0; i < 8; ++i) split2(va[i], hs[i], ls[i]);
            *reinterpret_cast<bf16x8*>(&As_h[row * 32 + c8]) = *reinterpret_cast<bf16x8*>(&hs[0]);
            *reinterpret_cast<bf16x8*>(&As_l[row * 32 + c8]) = *reinterpret_cast<bf16x8*>(&ls[0]);
        } else {
            gload16(Ah + (size_t)(row0 + arow16) * K + k0 + acol, &As_h[wid * 512]);
            gload16(Al + (size_t)(row0 + arow16) * K + k0 + acol, &As_l[wid * 512]);
        }
        // ---- stage B (tables, both paths) ----
        gload16(Bh + (size_t)brow32 * K + k0 + acol, &Bs_h[wid * 1024]);
        gload16(Bh + (size_t)(brow32 + 16) * K + k0 + acol, &Bs_h[wid * 1024 + 512]);
        gload16(Bl + (size_t)brow32 * K + k0 + acol, &Bs_l[wid * 1024]);
        gload16(Bl + (size_t)(brow32 + 16) * K + k0 + acol, &Bs_l[wid * 1024 + 512]);
        __syncthreads();

        bf16x8 ah[4], av[4];
#pragma unroll
        for (int q = 0; q < 4; ++q) {
            int arow = (wm * 64 + q * 16 + lr) * 32 + lg * 8;
            ah[q] = *reinterpret_cast<const bf16x8*>(&As_h[arow]);
            av[q] = *reinterpret_cast<const bf16x8*>(&As_l[arow]);
        }
#pragma unroll
        for (int nt = 0; nt < 4; ++nt) {
            int brow = (wn * 64 + nt * 16 + lr) * 32 + lg * 8;
            bf16x8 bh = *reinterpret_cast<const bf16x8*>(&Bs_h[brow]);
            bf16x8 bv = *reinterpret_cast<const bf16x8*>(&Bs_l[brow]);
#pragma unroll
            for (int mt = 0; mt < 4; ++mt) {
                acc[mt][nt] = __builtin_amdgcn_mfma_f32_16x16x32_bf16(ah[mt], bh, acc[mt][nt], 0, 0, 0);
                acc[mt][nt] = __builtin_amdgcn_mfma_f32_16x16x32_bf16(ah[mt], bv, acc[mt][nt], 0, 0, 0);
                acc[mt][nt] = __builtin_amdgcn_mfma_f32_16x16x32_bf16(av[mt], bh, acc[mt][nt], 0, 0, 0);
            }
        }
        __syncthreads();
    }

    // epilogue: wave wn spans exactly head wn (cols wn*64..+64)
    const int head = wn;
    float alv[4], arv[4];
    if (ELER) {
#pragma unroll
        for (int nt = 0; nt < 4; ++nt) {
            alv[nt] = al[head * 64 + nt * 16 + lr];
            arv[nt] = ar[head * 64 + nt * 16 + lr];
        }
    }
#pragma unroll
    for (int mt = 0; mt < 4; ++mt) {
#pragma unroll
        for (int r = 0; r < 4; ++r) {
            int row = row0 + wm * 64 + mt * 16 + lg * 4 + r;
            bool valid = row < M;
            float sl = 0.f, sr_ = 0.f;
#pragma unroll
            for (int nt = 0; nt < 4; ++nt) {
                float v = acc[mt][nt][r];
                if (TANH) v = fast_tanh(v);
                if (valid) {
                    size_t ci = (size_t)row * 256 + wn * 64 + nt * 16 + lr;
                    if (SPLIT_OUT) {
                        short hh, ll;
                        split2(v, hh, ll);
                        Oh[ci] = hh;
                        Ol[ci] = ll;
                    } else {
                        O16[ci] = __float2half(v);
                    }
                }
                if (ELER) { sl = fmaf(v, alv[nt], sl); sr_ = fmaf(v, arv[nt], sr_); }
            }
            if (ELER) {
#pragma unroll
                for (int mask = 1; mask < 16; mask <<= 1) {
                    sl  += __shfl_xor(sl, mask, 16);
                    sr_ += __shfl_xor(sr_, mask, 16);
                }
                if (valid && lr == 0) {
                    el[row * 4 + head] = sl;
                    er[row * 4 + head] = sr_;
                }
            }
        }
    }
}

// ---------------- CSR build ------------------------------------------------
__global__ void count_deg_kernel(const int* __restrict__ dst, int* __restrict__ deg, int E) {
    int i = blockIdx.x * blockDim.x + threadIdx.x;
    if (i < E) atomicAdd(&deg[dst[i]], 1);
}

__global__ __launch_bounds__(1024) void scan_kernel(const int* __restrict__ deg,
                                                    int* __restrict__ offs,
                                                    int* __restrict__ cursor, int n) {
    __shared__ int wsum[16];
    const int tid = threadIdx.x, lane = tid & 63, wv = tid >> 6;
    int carry = 0;
    for (int base = 0; base < n; base += 4096) {
        int i = base + tid * 4;
        int v0 = 0, v1 = 0, v2 = 0, v3 = 0;
        if (i + 3 < n) {
            int4 q = *reinterpret_cast<const int4*>(&deg[i]);
            v0 = q.x; v1 = q.y; v2 = q.z; v3 = q.w;
        } else if (i < n) {
            v0 = deg[i];
            if (i + 1 < n) v1 = deg[i + 1];
            if (i + 2 < n) v2 = deg[i + 2];
        }
        int s = v0 + v1 + v2 + v3;
        int incl = s;
#pragma unroll
        for (int d = 1; d < 64; d <<= 1) {
            int t = __shfl_up(incl, d, 64);
            if (lane >= d) incl += t;
        }
        if (lane == 63) wsum[wv] = incl;
        __syncthreads();
        int woff = 0, tot = 0;
#pragma unroll
        for (int w2 = 0; w2 < 16; ++w2) {
            int x = wsum[w2];
            if (w2 < wv) woff += x;
            tot += x;
        }
        int excl = carry + woff + incl - s;
        if (i < n) {
            int p0 = excl, p1 = p0 + v0, p2 = p1 + v1, p3 = p2 + v2;
            offs[i] = p0; cursor[i] = p0;
            if (i + 1 < n) { offs[i + 1] = p1; cursor[i + 1] = p1; }
            if (i + 2 < n) { offs[i + 2] = p2; cursor[i + 2] = p2; }
            if (i + 3 < n) { offs[i + 3] = p3; cursor[i + 3] = p3; }
        }
        carry += tot;
        __syncthreads();
    }
    if (tid == 0) offs[n] = carry;
}

__global__ void fill_csr_kernel(const int* __restrict__ src, const int* __restrict__ dst,
                                int* __restrict__ cursor, int* __restrict__ srcs_sorted, int E) {
    int i = blockIdx.x * blockDim.x + threadIdx.x;
    if (i < E) {
        int d = dst[i];
        int pos = atomicAdd(&cursor[d], 1);
        srcs_sorted[pos] = src[i];
    }
}

// ---------------- GAT aggregation: wave/node, fp16 rows, inline weights ----
template<bool FINAL>
__global__ __launch_bounds__(256) void gat_agg_kernel(const __half* __restrict__ feat,
                                                      const float* __restrict__ el,
                                                      const float* __restrict__ er,
                                                      const int* __restrict__ srcs,
                                                      const int* __restrict__ offs,
                                                      const float* __restrict__ bias,
                                                      float* __restrict__ out,
                                                      short* __restrict__ Gh,
                                                      short* __restrict__ Gl, int N) {
    const int tid = threadIdx.x;
    const int w = tid >> 6, l = tid & 63;
    const int n = blockIdx.x * 4 + w;
    if (n >= N) return;
    const int h = l >> 4;
    const int begin = offs[n];
    const int deg = offs[n + 1] - begin;
    const float erh = er[n * 4 + h];
    const __half* fbase = feat + (size_t)l * 4;

    float4 acc = make_float4(0.f, 0.f, 0.f, 0.f);
    float z = 0.f;

    for (int j = 0; j < deg; j += 8) {
        const int rem = deg - j;
        const int nb = __builtin_amdgcn_readfirstlane(begin + j);
        const int s0 = srcs[nb + 0];
        const int s1 = (rem > 1) ? srcs[nb + 1] : 0;
        const int s2 = (rem > 2) ? srcs[nb + 2] : 0;
        const int s3 = (rem > 3) ? srcs[nb + 3] : 0;
        const int s4 = (rem > 4) ? srcs[nb + 4] : 0;
        const int s5 = (rem > 5) ? srcs[nb + 5] : 0;
        const int s6 = (rem > 6) ? srcs[nb + 6] : 0;
        const int s7 = (rem > 7) ? srcs[nb + 7] : 0;
        const float4 q0 = *reinterpret_cast<const float4*>(&el[(size_t)s0 * 4]);
        const float4 q1 = *reinterpret_cast<const float4*>(&el[(size_t)s1 * 4]);
        const float4 q2 = *reinterpret_cast<const float4*>(&el[(size_t)s2 * 4]);
        const float4 q3 = *reinterpret_cast<const float4*>(&el[(size_t)s3 * 4]);
        const float4 q4 = *reinterpret_cast<const float4*>(&el[(size_t)s4 * 4]);
        const float4 q5 = *reinterpret_cast<const float4*>(&el[(size_t)s5 * 4]);
        const float4 q6 = *reinterpret_cast<const float4*>(&el[(size_t)s6 * 4]);
        const float4 q7 = *reinterpret_cast<const float4*>(&el[(size_t)s7 * 4]);
        const uint2 u0 = *reinterpret_cast<const uint2*>(fbase + (size_t)s0 * 256);
        const uint2 u1 = *reinterpret_cast<const uint2*>(fbase + (size_t)s1 * 256);
        const uint2 u2 = *reinterpret_cast<const uint2*>(fbase + (size_t)s2 * 256);
        const uint2 u3 = *reinterpret_cast<const uint2*>(fbase + (size_t)s3 * 256);
        const uint2 u4 = *reinterpret_cast<const uint2*>(fbase + (size_t)s4 * 256);
        const uint2 u5 = *reinterpret_cast<const uint2*>(fbase + (size_t)s5 * 256);
        const uint2 u6 = *reinterpret_cast<const uint2*>(fbase + (size_t)s6 * 256);
        const uint2 u7 = *reinterpret_cast<const uint2*>(fbase + (size_t)s7 * 256);

        const float e0 = __expf(leaky02(sel_head(q0, h) + erh));
        const float e1 = (rem > 1) ? __expf(leaky02(sel_head(q1, h) + erh)) : 0.f;
        const float e2 = (rem > 2) ? __expf(leaky02(sel_head(q2, h) + erh)) : 0.f;
        const float e3 = (rem > 3) ? __expf(leaky02(sel_head(q3, h) + erh)) : 0.f;
        const float e4 = (rem > 4) ? __expf(leaky02(sel_head(q4, h) + erh)) : 0.f;
        const float e5 = (rem > 5) ? __expf(leaky02(sel_head(q5, h) + erh)) : 0.f;
        const float e6 = (rem > 6) ? __expf(leaky02(sel_head(q6, h) + erh)) : 0.f;
        const float e7 = (rem > 7) ? __expf(leaky02(sel_head(q7, h) + erh)) : 0.f;
        z += ((e0 + e1) + (e2 + e3)) + ((e4 + e5) + (e6 + e7));

        auto fma4 = [&](float e, uint2 u) {
            const __half2* hp = reinterpret_cast<const __half2*>(&u);
            float2 a = __half22float2(hp[0]);
            float2 b = __half22float2(hp[1]);
            acc.x = fmaf(e, a.x, acc.x); acc.y = fmaf(e, a.y, acc.y);
            acc.z = fmaf(e, b.x, acc.z); acc.w = fmaf(e, b.y, acc.w);
        };
        fma4(e0, u0); fma4(e1, u1); fma4(e2, u2); fma4(e3, u3);
        fma4(e4, u4); fma4(e5, u5); fma4(e6, u6); fma4(e7, u7);
    }

    const float rz = (z > 0.f) ? __builtin_amdgcn_rcpf(z) : 0.f;
    const float4 bv = *reinterpret_cast<const float4*>(&bias[l * 4]);
    float4 v;
    v.x = fmaf(acc.x, rz, bv.x);
    v.y = fmaf(acc.y, rz, bv.y);
    v.z = fmaf(acc.z, rz, bv.z);
    v.w = fmaf(acc.w, rz, bv.w);
    v.x = v.x > 0.f ? v.x : expm1f(v.x);
    v.y = v.y > 0.f ? v.y : expm1f(v.y);
    v.z = v.z > 0.f ? v.z : expm1f(v.z);
    v.w = v.w > 0.f ? v.w : expm1f(v.w);

    if (!FINAL) {
        short4 hh, ll;
        split2(v.x, hh.x, ll.x);
        split2(v.y, hh.y, ll.y);
        split2(v.z, hh.z, ll.z);
        split2(v.w, hh.w, ll.w);
        *reinterpret_cast<short4*>(&Gh[(size_t)n * 256 + l * 4]) = hh;
        *reinterpret_cast<short4*>(&Gl[(size_t)n * 256 + l * 4]) = ll;
    } else {
        v.x += __shfl_down(v.x, 32, 64); v.y += __shfl_down(v.y, 32, 64);
        v.z += __shfl_down(v.z, 32, 64); v.w += __shfl_down(v.w, 32, 64);
        v.x += __shfl_down(v.x, 16, 64); v.y += __shfl_down(v.y, 16, 64);
        v.z += __shfl_down(v.z, 16, 64); v.w += __shfl_down(v.w, 16, 64);
        if (l < 16) {
            float4 o;
            o.x = 0.25f * v.x; o.y = 0.25f * v.y; o.z = 0.25f * v.z; o.w = 0.25f * v.w;
            *reinterpret_cast<float4*>(&out[(size_t)n * 64 + l * 4]) = o;
        }
    }
}

// ---------------------------------------------------------------------------
extern "C" void kernel_launch(void* const* d_in, const int* in_sizes, int n_in,
                              void* d_out, int out_size, void* d_ws, size_t ws_size,
                              hipStream_t stream) {
    const float* x_feat = (const float*)d_in[0];
    const float* W_fc   = (const float*)d_in[1];
    const float* W1     = (const float*)d_in[2];
    const float* al1    = (const float*)d_in[3];
    const float* ar1    = (const float*)d_in[4];
    const float* b1     = (const float*)d_in[5];
    const float* W2     = (const float*)d_in[6];
    const float* al2    = (const float*)d_in[7];
    const float* ar2    = (const float*)d_in[8];
    const float* b2     = (const float*)d_in[9];
    const int*   src    = (const int*)d_in[10];
    const int*   dst    = (const int*)d_in[11];
    float* out = (float*)d_out;

    const int N = in_sizes[0] / 128;   // 50000
    const int E = in_sizes[10];        // 800000
    const int NB = (N + 127) / 128;    // 391
    const int M_pad = NB * 128;        // 50048

    char* ws = (char*)d_ws;
    size_t off = 0;
    auto alloc = [&](size_t bytes) -> void* {
        off = (off + 255) & ~(size_t)255;
        void* p = ws + off;
        off += bytes;
        return p;
    };
    short* Hh   = (short*)alloc((size_t)M_pad * 256 * 2);  // h tables; reused as g1
    short* Hl   = (short*)alloc((size_t)M_pad * 256 * 2);
    __half* f16 = (__half*)alloc((size_t)M_pad * 256 * 2); // feat1/feat2 gather table
    float* el   = (float*)alloc((size_t)N * 4 * 4);
    float* er   = (float*)alloc((size_t)N * 4 * 4);
    int* deg    = (int*)alloc((size_t)N * 4);
    int* offs   = (int*)alloc((size_t)(N + 4) * 4);
    int* cursor = (int*)alloc((size_t)N * 4);
    int* srcs_sorted = (int*)alloc((size_t)(E + 8) * 4);
    short* Bfc_h = (short*)alloc((size_t)256 * 128 * 2);
    short* Bfc_l = (short*)alloc((size_t)256 * 128 * 2);
    short* B1_h  = (short*)alloc((size_t)256 * 256 * 2);
    short* B1_l  = (short*)alloc((size_t)256 * 256 * 2);
    short* B2_h  = (short*)alloc((size_t)256 * 256 * 2);
    short* B2_l  = (short*)alloc((size_t)256 * 256 * 2);

    const int eb = (E + 255) / 256;
    const int agrid = (N + 3) / 4;

    const int prep_threads = 128 * 256 + 2 * 256 * 256;   // 163840 (> N)
    // 1: prep (wsplit3 + zero deg)
    prep_kernel<<<(prep_threads + 255) / 256, 256, 0, stream>>>(
        W_fc, Bfc_h, Bfc_l, W1, B1_h, B1_l, W2, B2_h, B2_l, deg, N);
    // 2-4: CSR build (by dst)
    count_deg_kernel<<<eb, 256, 0, stream>>>(dst, deg, E);
    scan_kernel<<<1, 1024, 0, stream>>>(deg, offs, cursor, N);
    fill_csr_kernel<<<eb, 256, 0, stream>>>(src, dst, cursor, srcs_sorted, E);
    // 5: h = tanh(x @ W_fc) -> split bf16 tables (fp32 A, in-kernel split)
    mfma_gemm_kernel<128, true, true, false, true><<<NB, 512, 0, stream>>>(
        x_feat, nullptr, nullptr, Bfc_h, Bfc_l, Hh, Hl, nullptr, N,
        nullptr, nullptr, nullptr, nullptr);
    // 6: feat1 = h @ W1 -> fp16 gather table (+ el/er)
    mfma_gemm_kernel<256, false, false, true, false><<<NB, 512, 0, stream>>>(
        nullptr, Hh, Hl, B1_h, B1_l, nullptr, nullptr, f16, N, al1, ar1, el, er);
    // 7: g1 -> split bf16 tables (reuse Hh/Hl)
    gat_agg_kernel<false><<<agrid, 256, 0, stream>>>(
        f16, el, er, srcs_sorted, offs, b1, nullptr, Hh, Hl, N);
    // 8: feat2 = g1 @ W2 -> fp16 gather table (+ el/er)
    mfma_gemm_kernel<256, false, false, true, false><<<NB, 512, 0, stream>>>(
        nullptr, Hh, Hl, B2_h, B2_l, nullptr, nullptr, f16, N, al2, ar2, el, er);
    // 9: final aggregation + head mean -> out
    gat_agg_kernel<true><<<agrid, 256, 0, stream>>>(
        f16, el, er, srcs_sorted, offs, b2, out, nullptr, nullptr, N);
}